// Round 8
// baseline (413.135 us; speedup 1.0000x reference)
//
#include <hip/hip_runtime.h>
#include <hip/hip_bf16.h>
#include <cstdint>
#include <cstddef>

// ---------------------------------------------------------------------------
// GAT 2-layer forward. N=50000, E=800000 (+N self loops), H=8 heads.
// Layer1: Fin=128 -> 8x32 (=256), lrelu(0.2). Layer2: 256 -> 8x4 (=32).
// R7: edge softmax weights precomputed per (edge,head) into wT[h][pos]
// (CSR order) by k_edge_w; CSR rows padded to multiples of 4 with w=0
// dummy edges (dst=-1 marker) -> agg inner loops do aligned float4 wT
// reads, no exp / no ds_bpermute / no lane<8 divergence / no predication;
// denom is a plain per-lane running sum. Agg blocks 128 thr (2 waves) for
// degree-variance load balance.
// ---------------------------------------------------------------------------

__device__ __forceinline__ float lrelu(float a) { return a > 0.f ? a : 0.2f * a; }

__device__ __forceinline__ unsigned short f2bf(float f) {
  unsigned u = __float_as_uint(f);
  unsigned r = (u + 0x7fff + ((u >> 16) & 1)) >> 16;  // RNE
  return (unsigned short)r;
}
__device__ __forceinline__ float bf_lo(unsigned q) { return __uint_as_float(q << 16); }
__device__ __forceinline__ float bf_hi(unsigned q) { return __uint_as_float(q & 0xffff0000u); }

typedef __attribute__((ext_vector_type(8))) short bf16x8;
typedef __attribute__((ext_vector_type(4))) float f32x4;

// -------------------- CSR build (rows padded to %4) --------------------

__global__ __launch_bounds__(256) void k_hist(const int* __restrict__ dste, int E, int n,
                                              int* __restrict__ cnt) {
  int t = blockIdx.x * 256 + threadIdx.x;
  if (t >= E + n) return;
  int d = (t < E) ? dste[t] : (t - E);   // self-loop for node t-E
  atomicAdd(&cnt[d], 1);
}

__global__ __launch_bounds__(256) void k_scan1(const int* __restrict__ cnt, int n,
                                               int* __restrict__ bsum) {
  __shared__ int sb[256];
  int i0 = blockIdx.x * 1024 + threadIdx.x * 4;
  int s = 0;
#pragma unroll
  for (int j = 0; j < 4; j++) {
    int i = i0 + j;
    if (i < n) s += (cnt[i] + 3) & ~3;   // padded count
  }
  sb[threadIdx.x] = s;
  __syncthreads();
  for (int off = 128; off > 0; off >>= 1) {
    if (threadIdx.x < off) sb[threadIdx.x] += sb[threadIdx.x + off];
    __syncthreads();
  }
  if (threadIdx.x == 0) bsum[blockIdx.x] = sb[0];
}

__global__ void k_scan2(const int* __restrict__ bsum, int nb, int* __restrict__ boff,
                        int* __restrict__ row_ptr, int n) {
  if (threadIdx.x == 0 && blockIdx.x == 0) {
    int run = 0;
    for (int j = 0; j < nb; j++) { boff[j] = run; run += bsum[j]; }
    row_ptr[n] = run;
  }
}

__global__ __launch_bounds__(256) void k_scan3(const int* __restrict__ cnt,
                                               const int* __restrict__ boff, int n,
                                               int* __restrict__ row_ptr,
                                               int* __restrict__ cursor) {
  __shared__ int sb[256];
  int i0 = blockIdx.x * 1024 + threadIdx.x * 4;
  int c[4];
  int s = 0;
#pragma unroll
  for (int j = 0; j < 4; j++) {
    int i = i0 + j;
    c[j] = (i < n) ? ((cnt[i] + 3) & ~3) : 0;   // padded count
    s += c[j];
  }
  sb[threadIdx.x] = s;
  __syncthreads();
  for (int off = 1; off < 256; off <<= 1) {
    int add = (threadIdx.x >= off) ? sb[threadIdx.x - off] : 0;
    __syncthreads();
    sb[threadIdx.x] += add;
    __syncthreads();
  }
  int excl = sb[threadIdx.x] - s + boff[blockIdx.x];
#pragma unroll
  for (int j = 0; j < 4; j++) {
    int i = i0 + j;
    if (i < n) { row_ptr[i] = excl; cursor[i] = excl; excl += c[j]; }
  }
}

// srcs pre-memset to 0, dsts pre-memset to -1 (0xFF); pads keep those.
__global__ __launch_bounds__(256) void k_scatter(const int* __restrict__ srce,
                                                 const int* __restrict__ dste, int E, int n,
                                                 int* __restrict__ cursor,
                                                 int* __restrict__ srcs,
                                                 int* __restrict__ dsts) {
  int t = blockIdx.x * 256 + threadIdx.x;
  if (t >= E + n) return;
  int s, d;
  if (t < E) { s = srce[t]; d = dste[t]; } else { s = d = t - E; }
  int pos = atomicAdd(&cursor[d], 1);
  srcs[pos] = s;
  dsts[pos] = d;
}

// -------------------- edge weights: wT[h][pos] --------------------

__global__ __launch_bounds__(256) void k_edge_w(const int* __restrict__ srcs,
                                                const int* __restrict__ dsts,
                                                const float* __restrict__ asrc,
                                                const float* __restrict__ adst,
                                                float* __restrict__ wT,
                                                int P4cap, int Ppad) {
  int p = blockIdx.x * 256 + threadIdx.x;
  if (p >= P4cap) return;
  int h = blockIdx.y;
  int dd = dsts[p];
  int ss = srcs[p];
  float w = 0.f;
  if (dd >= 0) w = __expf(lrelu(asrc[ss * 8 + h] + adst[dd * 8 + h]));
  wT[(size_t)h * Ppad + p] = w;
}

// -------------------- W1 transpose to bf16 (once) --------------------

__global__ __launch_bounds__(256) void k_w1t(const float* __restrict__ W,
                                             unsigned short* __restrict__ WT) {
  int t = blockIdx.x * 256 + threadIdx.x;  // 32768 total
  int k = t >> 8;
  int nn = t & 255;
  WT[nn * 128 + k] = f2bf(W[k * 256 + nn]);
}

// -------------------- GEMM1: bf16 MFMA + fused alpha epilogue ------------

__global__ __launch_bounds__(256) void gemm1_mfma(const float* __restrict__ X,
                                                  const unsigned short* __restrict__ WT,
                                                  const float* __restrict__ a_src,
                                                  const float* __restrict__ a_dst,
                                                  unsigned short* __restrict__ h1,
                                                  float* __restrict__ a_s1,
                                                  float* __restrict__ a_d1,
                                                  int M) {
  __shared__ unsigned short As[64 * 136];
  __shared__ unsigned short Bs[256 * 72];
  const int row0 = blockIdx.x * 64;
  const int tid = threadIdx.x;
  const int wv = tid >> 6, lane = tid & 63;
  const int quad = lane >> 4, l15 = lane & 15;
  const int colw = wv * 64;

#pragma unroll
  for (int i = 0; i < 8; i++) {
    int j = tid + 256 * i;
    int r = j >> 5;
    int c4 = (j & 31) * 4;
    float4 v = make_float4(0.f, 0.f, 0.f, 0.f);
    if (row0 + r < M) v = *(const float4*)&X[(size_t)(row0 + r) * 128 + c4];
    uint2 p;
    p.x = (unsigned)f2bf(v.x) | ((unsigned)f2bf(v.y) << 16);
    p.y = (unsigned)f2bf(v.z) | ((unsigned)f2bf(v.w) << 16);
    *(uint2*)&As[r * 136 + c4] = p;
  }

  f32x4 acc[16];
#pragma unroll
  for (int i = 0; i < 16; i++) acc[i] = (f32x4)0.f;

  for (int kc = 0; kc < 128; kc += 64) {
    __syncthreads();
#pragma unroll
    for (int i = 0; i < 8; i++) {
      int j = tid + 256 * i;
      int nn = j >> 3;
      int kg = (j & 7) * 8;
      *(uint4*)&Bs[nn * 72 + kg] = *(const uint4*)&WT[nn * 128 + kc + kg];
    }
    __syncthreads();
#pragma unroll
    for (int ks = 0; ks < 64; ks += 32) {
      bf16x8 af[4], bfr[4];
#pragma unroll
      for (int mi = 0; mi < 4; mi++)
        af[mi] = *(const bf16x8*)&As[(mi * 16 + l15) * 136 + kc + ks + quad * 8];
#pragma unroll
      for (int ni = 0; ni < 4; ni++)
        bfr[ni] = *(const bf16x8*)&Bs[(colw + ni * 16 + l15) * 72 + ks + quad * 8];
#pragma unroll
      for (int mi = 0; mi < 4; mi++)
#pragma unroll
        for (int ni = 0; ni < 4; ni++)
          acc[mi * 4 + ni] = __builtin_amdgcn_mfma_f32_16x16x32_bf16(
              af[mi], bfr[ni], acc[mi * 4 + ni], 0, 0, 0);
    }
  }

  float as_[4], ad_[4];
#pragma unroll
  for (int ni = 0; ni < 4; ni++) {
    int nn = colw + ni * 16 + l15;
    as_[ni] = a_src[nn];
    ad_[ni] = a_dst[nn];
  }
  const int h0 = colw >> 5;
#pragma unroll
  for (int mi = 0; mi < 4; mi++) {
#pragma unroll
    for (int r = 0; r < 4; r++) {
      int m = row0 + mi * 16 + quad * 4 + r;
      bool valid = (m < M);
      if (valid) {
#pragma unroll
        for (int ni = 0; ni < 4; ni++)
          h1[(size_t)m * 256 + colw + ni * 16 + l15] = f2bf(acc[mi * 4 + ni][r]);
      }
      float s0 = fmaf(acc[mi * 4 + 0][r], as_[0], acc[mi * 4 + 1][r] * as_[1]);
      float s1 = fmaf(acc[mi * 4 + 2][r], as_[2], acc[mi * 4 + 3][r] * as_[3]);
      float d0 = fmaf(acc[mi * 4 + 0][r], ad_[0], acc[mi * 4 + 1][r] * ad_[1]);
      float d1 = fmaf(acc[mi * 4 + 2][r], ad_[2], acc[mi * 4 + 3][r] * ad_[3]);
#pragma unroll
      for (int mk = 1; mk <= 8; mk <<= 1) {
        s0 += __shfl_xor(s0, mk);
        s1 += __shfl_xor(s1, mk);
        d0 += __shfl_xor(d0, mk);
        d1 += __shfl_xor(d1, mk);
      }
      if (l15 == 0 && valid) {
        a_s1[m * 8 + h0]     = s0;
        a_s1[m * 8 + h0 + 1] = s1;
        a_d1[m * 8 + h0]     = d0;
        a_d1[m * 8 + h0 + 1] = d1;
      }
    }
  }
}

// -------------------- GEMM2 + alpha epilogue (x2 in bf16) --------------------

__global__ __launch_bounds__(256) void gemm2(const unsigned short* __restrict__ Xb,
                                             const float* __restrict__ W,
                                             const float* __restrict__ a_src,
                                             const float* __restrict__ a_dst,
                                             float* __restrict__ h2,
                                             float* __restrict__ a_s2,
                                             float* __restrict__ a_d2, int M) {
  __shared__ float lx[64 * 132];
  int row0 = blockIdx.x * 64;
  int tc = threadIdx.x & 7;
  int tr = threadIdx.x >> 3;
  float4 acc[2];
  acc[0] = make_float4(0.f, 0.f, 0.f, 0.f);
  acc[1] = make_float4(0.f, 0.f, 0.f, 0.f);
  for (int kk = 0; kk < 256; kk += 128) {
    __syncthreads();
#pragma unroll
    for (int i = 0; i < 8; i++) {
      int j = threadIdx.x + 256 * i;
      int r = j >> 5;
      int c = (j & 31) * 4;
      float4 v = make_float4(0.f, 0.f, 0.f, 0.f);
      if (row0 + r < M) {
        uint2 q = *(const uint2*)&Xb[(size_t)(row0 + r) * 256 + kk + c];
        v = make_float4(bf_lo(q.x), bf_hi(q.x), bf_lo(q.y), bf_hi(q.y));
      }
      *(float4*)&lx[r * 132 + c] = v;
    }
    __syncthreads();
    for (int k = 0; k < 128; k++) {
      float4 w4 = *(const float4*)&W[(kk + k) * 32 + tc * 4];
#pragma unroll
      for (int i = 0; i < 2; i++) {
        float xv = lx[(tr * 2 + i) * 132 + k];
        acc[i].x = fmaf(xv, w4.x, acc[i].x);
        acc[i].y = fmaf(xv, w4.y, acc[i].y);
        acc[i].z = fmaf(xv, w4.z, acc[i].z);
        acc[i].w = fmaf(xv, w4.w, acc[i].w);
      }
    }
  }
  float4 asv = *(const float4*)&a_src[tc * 4];
  float4 adv = *(const float4*)&a_dst[tc * 4];
#pragma unroll
  for (int i = 0; i < 2; i++) {
    int r = row0 + tr * 2 + i;
    if (r < M) {
      float ps = acc[i].x * asv.x;
      ps = fmaf(acc[i].y, asv.y, ps);
      ps = fmaf(acc[i].z, asv.z, ps);
      ps = fmaf(acc[i].w, asv.w, ps);
      float pd = acc[i].x * adv.x;
      pd = fmaf(acc[i].y, adv.y, pd);
      pd = fmaf(acc[i].z, adv.z, pd);
      pd = fmaf(acc[i].w, adv.w, pd);
      *(float4*)&h2[(size_t)r * 32 + tc * 4] = acc[i];
      a_s2[r * 8 + tc] = ps;
      a_d2[r * 8 + tc] = pd;
    }
  }
}

// -------------------- segment softmax + aggregation --------------------

// Layer 1: F=256 bf16. Weights from wT (precomputed, CSR order, pads w=0).
// Lane owns channels lane*4..+3, head = lane>>3. No exp / shfl / predication.
__global__ __launch_bounds__(128) void gat_agg_l1(const unsigned short* __restrict__ h,
                                                  const float* __restrict__ wT,
                                                  const int* __restrict__ row_ptr,
                                                  const int* __restrict__ srcs,
                                                  const float* __restrict__ bias,
                                                  unsigned short* __restrict__ out,
                                                  int n, int Ppad) {
  int wave = threadIdx.x >> 6;
  int lane = threadIdx.x & 63;
  int d = blockIdx.x * 2 + wave;
  if (d >= n) return;
  int begin = row_ptr[d];
  int end = row_ptr[d + 1];             // multiple-of-4 row
  const float* wrow = wT + (size_t)(lane >> 3) * Ppad;

  float denom = 0.f;
  float4 acc0 = make_float4(0.f, 0.f, 0.f, 0.f);
  float4 acc1 = make_float4(0.f, 0.f, 0.f, 0.f);
#define ACCA(ff, qq)                                        \
    acc0.x = fmaf(ff, bf_lo(qq.x), acc0.x);                 \
    acc0.y = fmaf(ff, bf_hi(qq.x), acc0.y);                 \
    acc0.z = fmaf(ff, bf_lo(qq.y), acc0.z);                 \
    acc0.w = fmaf(ff, bf_hi(qq.y), acc0.w);
#define ACCB(ff, qq)                                        \
    acc1.x = fmaf(ff, bf_lo(qq.x), acc1.x);                 \
    acc1.y = fmaf(ff, bf_hi(qq.x), acc1.y);                 \
    acc1.z = fmaf(ff, bf_lo(qq.y), acc1.z);                 \
    acc1.w = fmaf(ff, bf_hi(qq.y), acc1.w);

  int e = begin;
  for (; e + 16 <= end; e += 16) {
    int s[16];
#pragma unroll
    for (int j = 0; j < 16; j++) s[j] = srcs[e + j];
    float4 w0 = *(const float4*)&wrow[e];
    float4 w1 = *(const float4*)&wrow[e + 4];
    float4 w2 = *(const float4*)&wrow[e + 8];
    float4 w3 = *(const float4*)&wrow[e + 12];
    uint2 q[16];
#pragma unroll
    for (int j = 0; j < 16; j++) q[j] = *(const uint2*)&h[(size_t)s[j] * 256 + lane * 4];
    denom += (w0.x + w0.y + w0.z + w0.w) + (w1.x + w1.y + w1.z + w1.w) +
             (w2.x + w2.y + w2.z + w2.w) + (w3.x + w3.y + w3.z + w3.w);
    ACCA(w0.x, q[0])  ACCB(w0.y, q[1])  ACCA(w0.z, q[2])  ACCB(w0.w, q[3])
    ACCA(w1.x, q[4])  ACCB(w1.y, q[5])  ACCA(w1.z, q[6])  ACCB(w1.w, q[7])
    ACCA(w2.x, q[8])  ACCB(w2.y, q[9])  ACCA(w2.z, q[10]) ACCB(w2.w, q[11])
    ACCA(w3.x, q[12]) ACCB(w3.y, q[13]) ACCA(w3.z, q[14]) ACCB(w3.w, q[15])
  }
  for (; e < end; e += 4) {              // remainder is a multiple of 4
    int s[4];
#pragma unroll
    for (int j = 0; j < 4; j++) s[j] = srcs[e + j];
    float4 w0 = *(const float4*)&wrow[e];
    uint2 q[4];
#pragma unroll
    for (int j = 0; j < 4; j++) q[j] = *(const uint2*)&h[(size_t)s[j] * 256 + lane * 4];
    denom += (w0.x + w0.y) + (w0.z + w0.w);
    ACCA(w0.x, q[0]) ACCB(w0.y, q[1]) ACCA(w0.z, q[2]) ACCB(w0.w, q[3])
  }
#undef ACCA
#undef ACCB
  float4 acc;
  acc.x = acc0.x + acc1.x;
  acc.y = acc0.y + acc1.y;
  acc.z = acc0.z + acc1.z;
  acc.w = acc0.w + acc1.w;
  float inv = 1.f / (denom + 1e-16f);    // identical across the head group
  int f = lane * 4;
  float4 bv = *(const float4*)&bias[f];
  float rx = lrelu(acc.x * inv + bv.x);
  float ry = lrelu(acc.y * inv + bv.y);
  float rz = lrelu(acc.z * inv + bv.z);
  float rw = lrelu(acc.w * inv + bv.w);
  uint2 p;
  p.x = (unsigned)f2bf(rx) | ((unsigned)f2bf(ry) << 16);
  p.y = (unsigned)f2bf(rz) | ((unsigned)f2bf(rw) << 16);
  *(uint2*)&out[(size_t)d * 256 + f] = p;
}

// Layer 2: C=4, F=32. Weights from wT. 8 edges in parallel, unrolled x2.
__global__ __launch_bounds__(128) void gat_agg_l2(const float* __restrict__ h,
                                                  const float* __restrict__ wT,
                                                  const int* __restrict__ row_ptr,
                                                  const int* __restrict__ srcs,
                                                  const float* __restrict__ bias,
                                                  float* __restrict__ out,
                                                  int n, int Ppad) {
  int wave = threadIdx.x >> 6;
  int lane = threadIdx.x & 63;
  int d = blockIdx.x * 2 + wave;
  if (d >= n) return;
  int begin = row_ptr[d];
  int end = row_ptr[d + 1];
  int hh = lane & 7;
  int eg = lane >> 3;
  const float* wrow = wT + (size_t)hh * Ppad;

  float denom = 0.f;
  float4 acc = make_float4(0.f, 0.f, 0.f, 0.f);
  int base = begin;
  for (; base + 16 <= end; base += 16) {
    int eA = base + eg, eB = base + 8 + eg;
    int sA = srcs[eA], sB = srcs[eB];
    float wA = wrow[eA], wB = wrow[eB];
    const float4 hA = *(const float4*)&h[(size_t)sA * 32 + hh * 4];
    const float4 hB = *(const float4*)&h[(size_t)sB * 32 + hh * 4];
    denom += wA + wB;
    acc.x = fmaf(wA, hA.x, acc.x); acc.y = fmaf(wA, hA.y, acc.y);
    acc.z = fmaf(wA, hA.z, acc.z); acc.w = fmaf(wA, hA.w, acc.w);
    acc.x = fmaf(wB, hB.x, acc.x); acc.y = fmaf(wB, hB.y, acc.y);
    acc.z = fmaf(wB, hB.z, acc.z); acc.w = fmaf(wB, hB.w, acc.w);
  }
  for (; base < end; base += 8) {
    int e = base + eg;
    if (e < end) {                       // rows are %4, not %8: predicate
      int s = srcs[e];
      float w = wrow[e];
      denom += w;
      const float4 hv = *(const float4*)&h[(size_t)s * 32 + hh * 4];
      acc.x = fmaf(w, hv.x, acc.x);
      acc.y = fmaf(w, hv.y, acc.y);
      acc.z = fmaf(w, hv.z, acc.z);
      acc.w = fmaf(w, hv.w, acc.w);
    }
  }
#pragma unroll
  for (int mask = 8; mask <= 32; mask <<= 1) {
    denom += __shfl_xor(denom, mask);
    acc.x += __shfl_xor(acc.x, mask);
    acc.y += __shfl_xor(acc.y, mask);
    acc.z += __shfl_xor(acc.z, mask);
    acc.w += __shfl_xor(acc.w, mask);
  }
  if (lane < 8) {
    float inv = 1.f / (denom + 1e-16f);
    int f = lane * 4;
    float4 bv = *(const float4*)&bias[f];
    float4 r;
    r.x = acc.x * inv + bv.x;
    r.y = acc.y * inv + bv.y;
    r.z = acc.z * inv + bv.z;
    r.w = acc.w * inv + bv.w;
    *(float4*)&out[(size_t)d * 32 + f] = r;
  }
}

// -------------------- launcher --------------------

extern "C" void kernel_launch(void* const* d_in, const int* in_sizes, int n_in,
                              void* d_out, int out_size, void* d_ws, size_t ws_size,
                              hipStream_t stream) {
  const float* x   = (const float*)d_in[0];
  const int*   ei  = (const int*)d_in[1];
  const float* W1  = (const float*)d_in[2];
  const float* as1 = (const float*)d_in[3];
  const float* ad1 = (const float*)d_in[4];
  const float* b1  = (const float*)d_in[5];
  const float* W2  = (const float*)d_in[6];
  const float* as2 = (const float*)d_in[7];
  const float* ad2 = (const float*)d_in[8];
  const float* b2  = (const float*)d_in[9];
  float* out = (float*)d_out;

  const int E = in_sizes[1] / 2;
  const int n = in_sizes[0] / 128;
  const int* srce = ei;
  const int* dste = ei + E;
  const int P4cap = ((E + 4 * n + 63) & ~63);   // padded-CSR capacity
  const int Ppad = P4cap;                        // wT row stride

  char* ws = (char*)d_ws;
  size_t off = 0;
  auto alloc = [&](size_t bytes) -> void* {
    void* p = ws + off;
    off = (off + bytes + 255) & ~(size_t)255;
    return p;
  };
  int* cnt      = (int*)alloc((size_t)n * 4);
  int* row_ptr  = (int*)alloc((size_t)(n + 1) * 4);
  int* cursor   = (int*)alloc((size_t)n * 4);
  int* bsum     = (int*)alloc(256 * 4);
  int* boff     = (int*)alloc(256 * 4);
  int* srcs     = (int*)alloc((size_t)P4cap * 4);
  int* dsts     = (int*)alloc((size_t)P4cap * 4);
  float* wT     = (float*)alloc((size_t)8 * Ppad * 4);
  unsigned short* h1  = (unsigned short*)alloc((size_t)n * 256 * 2);  // bf16
  unsigned short* w1t = (unsigned short*)alloc((size_t)256 * 128 * 2);
  float* a_s1   = (float*)alloc((size_t)n * 8 * 4);
  float* a_d1   = (float*)alloc((size_t)n * 8 * 4);
  unsigned short* x2 = (unsigned short*)alloc((size_t)n * 256 * 2);   // bf16
  float* h2     = (float*)alloc((size_t)n * 32 * 4);
  float* a_s2   = (float*)alloc((size_t)n * 8 * 4);
  float* a_d2   = (float*)alloc((size_t)n * 8 * 4);

  const int tot = E + n;
  hipMemsetAsync(cnt, 0, (size_t)n * 4, stream);
  hipMemsetAsync(srcs, 0, (size_t)P4cap * 4, stream);
  hipMemsetAsync(dsts, 0xFF, (size_t)P4cap * 4, stream);   // -1 = pad marker
  k_w1t<<<128, 256, 0, stream>>>(W1, w1t);
  k_hist<<<(tot + 255) / 256, 256, 0, stream>>>(dste, E, n, cnt);
  const int nb = (n + 1023) / 1024;
  k_scan1<<<nb, 256, 0, stream>>>(cnt, n, bsum);
  k_scan2<<<1, 64, 0, stream>>>(bsum, nb, boff, row_ptr, n);
  k_scan3<<<nb, 256, 0, stream>>>(cnt, boff, n, row_ptr, cursor);
  k_scatter<<<(tot + 255) / 256, 256, 0, stream>>>(srce, dste, E, n, cursor, srcs, dsts);

  gemm1_mfma<<<(n + 63) / 64, 256, 0, stream>>>(x, w1t, as1, ad1, h1, a_s1, a_d1, n);
  {
    dim3 g((P4cap + 255) / 256, 8);
    k_edge_w<<<g, 256, 0, stream>>>(srcs, dsts, a_s1, a_d1, wT, P4cap, Ppad);
  }
  gat_agg_l1<<<(n + 1) / 2, 128, 0, stream>>>(h1, wT, row_ptr, srcs, b1, x2, n, Ppad);

  gemm2<<<(n + 63) / 64, 256, 0, stream>>>(x2, W2, as2, ad2, h2, a_s2, a_d2, n);
  {
    dim3 g((P4cap + 255) / 256, 8);
    k_edge_w<<<g, 256, 0, stream>>>(srcs, dsts, a_s2, a_d2, wT, P4cap, Ppad);
  }
  gat_agg_l2<<<(n + 1) / 2, 128, 0, stream>>>(h2, wT, row_ptr, srcs, b2, out, n, Ppad);
}

// Round 10
// 313.169 us; speedup vs baseline: 1.3192x; 1.3192x over previous
//
#include <hip/hip_runtime.h>
#include <hip/hip_bf16.h>
#include <cstdint>
#include <cstddef>

// ---------------------------------------------------------------------------
// GAT 2-layer forward. N=50000, E=800000 (+N self loops), H=8 heads.
// Layer1: Fin=128 -> 8x32 (=256), lrelu(0.2). Layer2: 256 -> 8x4 (=32).
// R9: R8 + FIX of gemm2_mfma B-staging (was writing only 512 of 1024 uint4
// -> half of Bs uninitialized -> NaN). Staging now nn=j>>5, kg=(j&31)*8,
// 4 uint4/thread. Everything else identical to R8 (gemm1/gemm2 both bf16
// MFMA with fused alpha epilogues; agg kernels = proven R6 versions).
// ---------------------------------------------------------------------------

__device__ __forceinline__ float lrelu(float a) { return a > 0.f ? a : 0.2f * a; }

__device__ __forceinline__ unsigned short f2bf(float f) {
  unsigned u = __float_as_uint(f);
  unsigned r = (u + 0x7fff + ((u >> 16) & 1)) >> 16;  // RNE
  return (unsigned short)r;
}
__device__ __forceinline__ float bf_lo(unsigned q) { return __uint_as_float(q << 16); }
__device__ __forceinline__ float bf_hi(unsigned q) { return __uint_as_float(q & 0xffff0000u); }

typedef __attribute__((ext_vector_type(8))) short bf16x8;
typedef __attribute__((ext_vector_type(4))) float f32x4;

// -------------------- CSR build --------------------

__global__ __launch_bounds__(256) void k_hist(const int* __restrict__ dste, int E, int n,
                                              int* __restrict__ cnt) {
  int t = blockIdx.x * 256 + threadIdx.x;
  if (t >= E + n) return;
  int d = (t < E) ? dste[t] : (t - E);   // self-loop for node t-E
  atomicAdd(&cnt[d], 1);
}

__global__ __launch_bounds__(256) void k_scan1(const int* __restrict__ cnt, int n,
                                               int* __restrict__ bsum) {
  __shared__ int sb[256];
  int i0 = blockIdx.x * 1024 + threadIdx.x * 4;
  int s = 0;
#pragma unroll
  for (int j = 0; j < 4; j++) { int i = i0 + j; if (i < n) s += cnt[i]; }
  sb[threadIdx.x] = s;
  __syncthreads();
  for (int off = 128; off > 0; off >>= 1) {
    if (threadIdx.x < off) sb[threadIdx.x] += sb[threadIdx.x + off];
    __syncthreads();
  }
  if (threadIdx.x == 0) bsum[blockIdx.x] = sb[0];
}

__global__ void k_scan2(const int* __restrict__ bsum, int nb, int* __restrict__ boff,
                        int* __restrict__ row_ptr, int n) {
  if (threadIdx.x == 0 && blockIdx.x == 0) {
    int run = 0;
    for (int j = 0; j < nb; j++) { boff[j] = run; run += bsum[j]; }
    row_ptr[n] = run;
  }
}

__global__ __launch_bounds__(256) void k_scan3(const int* __restrict__ cnt,
                                               const int* __restrict__ boff, int n,
                                               int* __restrict__ row_ptr,
                                               int* __restrict__ cursor) {
  __shared__ int sb[256];
  int i0 = blockIdx.x * 1024 + threadIdx.x * 4;
  int c[4];
  int s = 0;
#pragma unroll
  for (int j = 0; j < 4; j++) { int i = i0 + j; c[j] = (i < n) ? cnt[i] : 0; s += c[j]; }
  sb[threadIdx.x] = s;
  __syncthreads();
  for (int off = 1; off < 256; off <<= 1) {
    int add = (threadIdx.x >= off) ? sb[threadIdx.x - off] : 0;
    __syncthreads();
    sb[threadIdx.x] += add;
    __syncthreads();
  }
  int excl = sb[threadIdx.x] - s + boff[blockIdx.x];
#pragma unroll
  for (int j = 0; j < 4; j++) {
    int i = i0 + j;
    if (i < n) { row_ptr[i] = excl; cursor[i] = excl; excl += c[j]; }
  }
}

__global__ __launch_bounds__(256) void k_scatter(const int* __restrict__ srce,
                                                 const int* __restrict__ dste, int E, int n,
                                                 int* __restrict__ cursor,
                                                 int* __restrict__ srcs) {
  int t = blockIdx.x * 256 + threadIdx.x;
  if (t >= E + n) return;
  int s, d;
  if (t < E) { s = srce[t]; d = dste[t]; } else { s = d = t - E; }
  int pos = atomicAdd(&cursor[d], 1);
  srcs[pos] = s;
}

// -------------------- weight pre-transposes (once) --------------------

// W1 [128][256] fp32 -> W1T [256][128] bf16.
__global__ __launch_bounds__(256) void k_w1t(const float* __restrict__ W,
                                             unsigned short* __restrict__ WT) {
  int t = blockIdx.x * 256 + threadIdx.x;  // 32768 total
  int k = t >> 8;
  int nn = t & 255;
  WT[nn * 128 + k] = f2bf(W[k * 256 + nn]);
}

// W2 [256][32] fp32 -> W2T [32][256] bf16.
__global__ __launch_bounds__(256) void k_w2t(const float* __restrict__ W,
                                             unsigned short* __restrict__ WT) {
  int t = blockIdx.x * 256 + threadIdx.x;  // 8192 total
  if (t >= 8192) return;
  int k = t >> 5;        // 0..255
  int nn = t & 31;       // 0..31
  WT[nn * 256 + k] = f2bf(W[k * 32 + nn]);
}

// -------------------- GEMM1: bf16 MFMA + fused alpha epilogue ------------

__global__ __launch_bounds__(256) void gemm1_mfma(const float* __restrict__ X,
                                                  const unsigned short* __restrict__ WT,
                                                  const float* __restrict__ a_src,
                                                  const float* __restrict__ a_dst,
                                                  unsigned short* __restrict__ h1,
                                                  float* __restrict__ a_s1,
                                                  float* __restrict__ a_d1,
                                                  int M) {
  __shared__ unsigned short As[64 * 136];
  __shared__ unsigned short Bs[256 * 72];
  const int row0 = blockIdx.x * 64;
  const int tid = threadIdx.x;
  const int wv = tid >> 6, lane = tid & 63;
  const int quad = lane >> 4, l15 = lane & 15;
  const int colw = wv * 64;

#pragma unroll
  for (int i = 0; i < 8; i++) {
    int j = tid + 256 * i;
    int r = j >> 5;
    int c4 = (j & 31) * 4;
    float4 v = make_float4(0.f, 0.f, 0.f, 0.f);
    if (row0 + r < M) v = *(const float4*)&X[(size_t)(row0 + r) * 128 + c4];
    uint2 p;
    p.x = (unsigned)f2bf(v.x) | ((unsigned)f2bf(v.y) << 16);
    p.y = (unsigned)f2bf(v.z) | ((unsigned)f2bf(v.w) << 16);
    *(uint2*)&As[r * 136 + c4] = p;
  }

  f32x4 acc[16];
#pragma unroll
  for (int i = 0; i < 16; i++) acc[i] = (f32x4)0.f;

  for (int kc = 0; kc < 128; kc += 64) {
    __syncthreads();
#pragma unroll
    for (int i = 0; i < 8; i++) {
      int j = tid + 256 * i;
      int nn = j >> 3;
      int kg = (j & 7) * 8;
      *(uint4*)&Bs[nn * 72 + kg] = *(const uint4*)&WT[nn * 128 + kc + kg];
    }
    __syncthreads();
#pragma unroll
    for (int ks = 0; ks < 64; ks += 32) {
      bf16x8 af[4], bfr[4];
#pragma unroll
      for (int mi = 0; mi < 4; mi++)
        af[mi] = *(const bf16x8*)&As[(mi * 16 + l15) * 136 + kc + ks + quad * 8];
#pragma unroll
      for (int ni = 0; ni < 4; ni++)
        bfr[ni] = *(const bf16x8*)&Bs[(colw + ni * 16 + l15) * 72 + ks + quad * 8];
#pragma unroll
      for (int mi = 0; mi < 4; mi++)
#pragma unroll
        for (int ni = 0; ni < 4; ni++)
          acc[mi * 4 + ni] = __builtin_amdgcn_mfma_f32_16x16x32_bf16(
              af[mi], bfr[ni], acc[mi * 4 + ni], 0, 0, 0);
    }
  }

  float as_[4], ad_[4];
#pragma unroll
  for (int ni = 0; ni < 4; ni++) {
    int nn = colw + ni * 16 + l15;
    as_[ni] = a_src[nn];
    ad_[ni] = a_dst[nn];
  }
  const int h0 = colw >> 5;
#pragma unroll
  for (int mi = 0; mi < 4; mi++) {
#pragma unroll
    for (int r = 0; r < 4; r++) {
      int m = row0 + mi * 16 + quad * 4 + r;
      bool valid = (m < M);
      if (valid) {
#pragma unroll
        for (int ni = 0; ni < 4; ni++)
          h1[(size_t)m * 256 + colw + ni * 16 + l15] = f2bf(acc[mi * 4 + ni][r]);
      }
      float s0 = fmaf(acc[mi * 4 + 0][r], as_[0], acc[mi * 4 + 1][r] * as_[1]);
      float s1 = fmaf(acc[mi * 4 + 2][r], as_[2], acc[mi * 4 + 3][r] * as_[3]);
      float d0 = fmaf(acc[mi * 4 + 0][r], ad_[0], acc[mi * 4 + 1][r] * ad_[1]);
      float d1 = fmaf(acc[mi * 4 + 2][r], ad_[2], acc[mi * 4 + 3][r] * ad_[3]);
#pragma unroll
      for (int mk = 1; mk <= 8; mk <<= 1) {
        s0 += __shfl_xor(s0, mk);
        s1 += __shfl_xor(s1, mk);
        d0 += __shfl_xor(d0, mk);
        d1 += __shfl_xor(d1, mk);
      }
      if (l15 == 0 && valid) {
        a_s1[m * 8 + h0]     = s0;
        a_s1[m * 8 + h0 + 1] = s1;
        a_d1[m * 8 + h0]     = d0;
        a_d1[m * 8 + h0 + 1] = d1;
      }
    }
  }
}

// -------------------- GEMM2: bf16 MFMA + fused alpha epilogue ------------

// x2[M,256] bf16 @ W2T[32][256] bf16 -> h2 fp32 [M,32] + a_s2/a_d2 [M,8].
__global__ __launch_bounds__(256) void gemm2_mfma(const unsigned short* __restrict__ Xb,
                                                  const unsigned short* __restrict__ W2T,
                                                  const float* __restrict__ a_src,
                                                  const float* __restrict__ a_dst,
                                                  float* __restrict__ h2,
                                                  float* __restrict__ a_s2,
                                                  float* __restrict__ a_d2, int M) {
  __shared__ unsigned short As[64 * 264];   // 64 rows x 256 (+8 pad) bf16
  __shared__ unsigned short Bs[32 * 264];   // 32 cols x 256 (+8 pad) bf16
  const int row0 = blockIdx.x * 64;
  const int tid = threadIdx.x;
  const int wv = tid >> 6, lane = tid & 63;
  const int quad = lane >> 4, l15 = lane & 15;

  // stage A: 64x256 bf16 = 2048 uint4 (8 bf16 each), 8/thread
#pragma unroll
  for (int i = 0; i < 8; i++) {
    int j = tid + 256 * i;
    int r = j >> 5;
    int c8 = (j & 31) * 8;     // bf16 index, 8 bf16 per uint4
    uint4 v = make_uint4(0, 0, 0, 0);
    if (row0 + r < M) v = *(const uint4*)&Xb[(size_t)(row0 + r) * 256 + c8];
    *(uint4*)&As[r * 264 + c8] = v;
  }
  // stage B: 32x256 bf16 = 1024 uint4, 4/thread  (R9 FIX: was 512 -> NaN)
#pragma unroll
  for (int i = 0; i < 4; i++) {
    int j = tid + 256 * i;     // 0..1023
    int nn = j >> 5;           // 0..31
    int kg = (j & 31) * 8;     // 0..248
    *(uint4*)&Bs[nn * 264 + kg] = *(const uint4*)&W2T[nn * 256 + kg];
  }
  __syncthreads();

  f32x4 acc[2];
  acc[0] = (f32x4)0.f;
  acc[1] = (f32x4)0.f;
  const int mr = wv * 16;
#pragma unroll
  for (int ks = 0; ks < 256; ks += 32) {
    bf16x8 af = *(const bf16x8*)&As[(mr + l15) * 264 + ks + quad * 8];
    bf16x8 b0 = *(const bf16x8*)&Bs[(l15) * 264 + ks + quad * 8];
    bf16x8 b1 = *(const bf16x8*)&Bs[(16 + l15) * 264 + ks + quad * 8];
    acc[0] = __builtin_amdgcn_mfma_f32_16x16x32_bf16(af, b0, acc[0], 0, 0, 0);
    acc[1] = __builtin_amdgcn_mfma_f32_16x16x32_bf16(af, b1, acc[1], 0, 0, 0);
  }

  // epilogue: h2 + alpha dots. D[m][c]: m = mr+quad*4+r, c = ni*16+l15.
  float as_[2], ad_[2];
#pragma unroll
  for (int ni = 0; ni < 2; ni++) {
    int c = ni * 16 + l15;
    as_[ni] = a_src[c];
    ad_[ni] = a_dst[c];
  }
#pragma unroll
  for (int r = 0; r < 4; r++) {
    int m = row0 + mr + quad * 4 + r;
    bool valid = (m < M);
    float s0 = acc[0][r] * as_[0];
    float s1 = acc[1][r] * as_[1];
    float d0 = acc[0][r] * ad_[0];
    float d1 = acc[1][r] * ad_[1];
#pragma unroll
    for (int mk = 1; mk <= 2; mk <<= 1) {
      s0 += __shfl_xor(s0, mk);
      s1 += __shfl_xor(s1, mk);
      d0 += __shfl_xor(d0, mk);
      d1 += __shfl_xor(d1, mk);
    }
    if (valid) {
      h2[(size_t)m * 32 + l15]      = acc[0][r];
      h2[(size_t)m * 32 + 16 + l15] = acc[1][r];
      if ((l15 & 3) == 0) {
        int hq = l15 >> 2;
        a_s2[m * 8 + hq]     = s0;
        a_s2[m * 8 + 4 + hq] = s1;
        a_d2[m * 8 + hq]     = d0;
        a_d2[m * 8 + 4 + hq] = d1;
      }
    }
  }
}

// -------------------- segment softmax + aggregation (R6, proven) ---------

__global__ __launch_bounds__(256) void gat_agg_l1(const unsigned short* __restrict__ h,
                                                  const float* __restrict__ asrc,
                                                  const float* __restrict__ adst,
                                                  const int* __restrict__ row_ptr,
                                                  const int* __restrict__ srcs,
                                                  const float* __restrict__ bias,
                                                  unsigned short* __restrict__ out, int n) {
  int wave = threadIdx.x >> 6;
  int lane = threadIdx.x & 63;
  int d = blockIdx.x * 4 + wave;
  if (d >= n) return;
  int begin = row_ptr[d];
  int end = row_ptr[d + 1];
  int hh = lane & 7;
  float ad = adst[d * 8 + hh];

  const int myhead = lane >> 3;
  float denom = 0.f;
  float4 acc0 = make_float4(0.f, 0.f, 0.f, 0.f);
  float4 acc1 = make_float4(0.f, 0.f, 0.f, 0.f);
#define ACCA(ff, qq)                                        \
    acc0.x = fmaf(ff, bf_lo(qq.x), acc0.x);                 \
    acc0.y = fmaf(ff, bf_hi(qq.x), acc0.y);                 \
    acc0.z = fmaf(ff, bf_lo(qq.y), acc0.z);                 \
    acc0.w = fmaf(ff, bf_hi(qq.y), acc0.w);
#define ACCB(ff, qq)                                        \
    acc1.x = fmaf(ff, bf_lo(qq.x), acc1.x);                 \
    acc1.y = fmaf(ff, bf_hi(qq.x), acc1.y);                 \
    acc1.z = fmaf(ff, bf_lo(qq.y), acc1.z);                 \
    acc1.w = fmaf(ff, bf_hi(qq.y), acc1.w);

  int e = begin;
  for (; e + 16 <= end; e += 16) {
    int s[16];
#pragma unroll
    for (int j = 0; j < 16; j++) s[j] = srcs[e + j];
    float w[16];
    if (lane < 8) {
#pragma unroll
      for (int j = 0; j < 16; j++) {
        w[j] = __expf(lrelu(asrc[s[j] * 8 + lane] + ad));
        denom += w[j];
      }
    } else {
#pragma unroll
      for (int j = 0; j < 16; j++) w[j] = 0.f;
    }
    uint2 q[16];
#pragma unroll
    for (int j = 0; j < 16; j++) q[j] = *(const uint2*)&h[(size_t)s[j] * 256 + lane * 4];
    float f[16];
#pragma unroll
    for (int j = 0; j < 16; j++) f[j] = __shfl(w[j], myhead);
#pragma unroll
    for (int j = 0; j < 16; j += 2) {
      ACCA(f[j], q[j])
      ACCB(f[j + 1], q[j + 1])
    }
  }
  for (; e < end; e += 8) {
    int s[8];
    float w[8];
#pragma unroll
    for (int j = 0; j < 8; j++) {
      int ee = e + j;
      s[j] = srcs[ee < end ? ee : end - 1];
    }
    if (lane < 8) {
#pragma unroll
      for (int j = 0; j < 8; j++) {
        float v = __expf(lrelu(asrc[s[j] * 8 + lane] + ad));
        w[j] = (e + j < end) ? v : 0.f;
        denom += w[j];
      }
    } else {
#pragma unroll
      for (int j = 0; j < 8; j++) w[j] = 0.f;
    }
    uint2 q[8];
#pragma unroll
    for (int j = 0; j < 8; j++) q[j] = *(const uint2*)&h[(size_t)s[j] * 256 + lane * 4];
    float f[8];
#pragma unroll
    for (int j = 0; j < 8; j++) f[j] = __shfl(w[j], myhead);
#pragma unroll
    for (int j = 0; j < 8; j += 2) {
      ACCA(f[j], q[j])
      ACCB(f[j + 1], q[j + 1])
    }
  }
#undef ACCA
#undef ACCB
  float4 acc;
  acc.x = acc0.x + acc1.x;
  acc.y = acc0.y + acc1.y;
  acc.z = acc0.z + acc1.z;
  acc.w = acc0.w + acc1.w;
  float dn = __shfl(denom, myhead) + 1e-16f;
  float inv = 1.f / dn;
  int f = lane * 4;
  float4 bv = *(const float4*)&bias[f];
  float rx = lrelu(acc.x * inv + bv.x);
  float ry = lrelu(acc.y * inv + bv.y);
  float rz = lrelu(acc.z * inv + bv.z);
  float rw = lrelu(acc.w * inv + bv.w);
  uint2 p;
  p.x = (unsigned)f2bf(rx) | ((unsigned)f2bf(ry) << 16);
  p.y = (unsigned)f2bf(rz) | ((unsigned)f2bf(rw) << 16);
  *(uint2*)&out[(size_t)d * 256 + f] = p;
}

__global__ __launch_bounds__(256) void gat_agg_l2(const float* __restrict__ h,
                                                  const float* __restrict__ asrc,
                                                  const float* __restrict__ adst,
                                                  const int* __restrict__ row_ptr,
                                                  const int* __restrict__ srcs,
                                                  const float* __restrict__ bias,
                                                  float* __restrict__ out, int n) {
  int wave = threadIdx.x >> 6;
  int lane = threadIdx.x & 63;
  int d = blockIdx.x * 4 + wave;
  if (d >= n) return;
  int begin = row_ptr[d];
  int end = row_ptr[d + 1];
  int hh = lane & 7;
  int eg = lane >> 3;
  float ad = adst[d * 8 + hh];

  float denom = 0.f;
  float4 acc = make_float4(0.f, 0.f, 0.f, 0.f);
  int base = begin;
  for (; base + 16 <= end; base += 16) {
    int sA = srcs[base + eg];
    int sB = srcs[base + 8 + eg];
    float aA = asrc[sA * 8 + hh];
    float aB = asrc[sB * 8 + hh];
    const float4 hA = *(const float4*)&h[(size_t)sA * 32 + hh * 4];
    const float4 hB = *(const float4*)&h[(size_t)sB * 32 + hh * 4];
    float wA = __expf(lrelu(aA + ad));
    float wB = __expf(lrelu(aB + ad));
    denom += wA + wB;
    acc.x = fmaf(wA, hA.x, acc.x); acc.y = fmaf(wA, hA.y, acc.y);
    acc.z = fmaf(wA, hA.z, acc.z); acc.w = fmaf(wA, hA.w, acc.w);
    acc.x = fmaf(wB, hB.x, acc.x); acc.y = fmaf(wB, hB.y, acc.y);
    acc.z = fmaf(wB, hB.z, acc.z); acc.w = fmaf(wB, hB.w, acc.w);
  }
  for (; base < end; base += 8) {
    int e = base + eg;
    if (e < end) {
      int s = srcs[e];
      float w = __expf(lrelu(asrc[s * 8 + hh] + ad));
      denom += w;
      const float4 hv = *(const float4*)&h[(size_t)s * 32 + hh * 4];
      acc.x = fmaf(w, hv.x, acc.x);
      acc.y = fmaf(w, hv.y, acc.y);
      acc.z = fmaf(w, hv.z, acc.z);
      acc.w = fmaf(w, hv.w, acc.w);
    }
  }
#pragma unroll
  for (int mask = 8; mask <= 32; mask <<= 1) {
    denom += __shfl_xor(denom, mask);
    acc.x += __shfl_xor(acc.x, mask);
    acc.y += __shfl_xor(acc.y, mask);
    acc.z += __shfl_xor(acc.z, mask);
    acc.w += __shfl_xor(acc.w, mask);
  }
  if (lane < 8) {
    float inv = 1.f / (denom + 1e-16f);
    int f = lane * 4;
    float4 bv = *(const float4*)&bias[f];
    float4 r;
    r.x = acc.x * inv + bv.x;
    r.y = acc.y * inv + bv.y;
    r.z = acc.z * inv + bv.z;
    r.w = acc.w * inv + bv.w;
    *(float4*)&out[(size_t)d * 32 + f] = r;
  }
}

// -------------------- launcher --------------------

extern "C" void kernel_launch(void* const* d_in, const int* in_sizes, int n_in,
                              void* d_out, int out_size, void* d_ws, size_t ws_size,
                              hipStream_t stream) {
  const float* x   = (const float*)d_in[0];
  const int*   ei  = (const int*)d_in[1];
  const float* W1  = (const float*)d_in[2];
  const float* as1 = (const float*)d_in[3];
  const float* ad1 = (const float*)d_in[4];
  const float* b1  = (const float*)d_in[5];
  const float* W2  = (const float*)d_in[6];
  const float* as2 = (const float*)d_in[7];
  const float* ad2 = (const float*)d_in[8];
  const float* b2  = (const float*)d_in[9];
  float* out = (float*)d_out;

  const int E = in_sizes[1] / 2;
  const int n = in_sizes[0] / 128;
  const int* srce = ei;
  const int* dste = ei + E;

  char* ws = (char*)d_ws;
  size_t off = 0;
  auto alloc = [&](size_t bytes) -> void* {
    void* p = ws + off;
    off = (off + bytes + 255) & ~(size_t)255;
    return p;
  };
  int* cnt      = (int*)alloc((size_t)n * 4);
  int* row_ptr  = (int*)alloc((size_t)(n + 1) * 4);
  int* cursor   = (int*)alloc((size_t)n * 4);
  int* bsum     = (int*)alloc(256 * 4);
  int* boff     = (int*)alloc(256 * 4);
  int* srcs     = (int*)alloc((size_t)(E + n) * 4);
  unsigned short* h1  = (unsigned short*)alloc((size_t)n * 256 * 2);  // bf16
  unsigned short* w1t = (unsigned short*)alloc((size_t)256 * 128 * 2);
  unsigned short* w2t = (unsigned short*)alloc((size_t)32 * 256 * 2);
  float* a_s1   = (float*)alloc((size_t)n * 8 * 4);
  float* a_d1   = (float*)alloc((size_t)n * 8 * 4);
  unsigned short* x2 = (unsigned short*)alloc((size_t)n * 256 * 2);   // bf16
  float* h2     = (float*)alloc((size_t)n * 32 * 4);
  float* a_s2   = (float*)alloc((size_t)n * 8 * 4);
  float* a_d2   = (float*)alloc((size_t)n * 8 * 4);

  const int tot = E + n;
  hipMemsetAsync(cnt, 0, (size_t)n * 4, stream);
  k_w1t<<<128, 256, 0, stream>>>(W1, w1t);
  k_w2t<<<32, 256, 0, stream>>>(W2, w2t);
  k_hist<<<(tot + 255) / 256, 256, 0, stream>>>(dste, E, n, cnt);
  const int nb = (n + 1023) / 1024;
  k_scan1<<<nb, 256, 0, stream>>>(cnt, n, bsum);
  k_scan2<<<1, 64, 0, stream>>>(bsum, nb, boff, row_ptr, n);
  k_scan3<<<nb, 256, 0, stream>>>(cnt, boff, n, row_ptr, cursor);
  k_scatter<<<(tot + 255) / 256, 256, 0, stream>>>(srce, dste, E, n, cursor, srcs);

  gemm1_mfma<<<(n + 63) / 64, 256, 0, stream>>>(x, w1t, as1, ad1, h1, a_s1, a_d1, n);
  gat_agg_l1<<<(n + 3) / 4, 256, 0, stream>>>(h1, a_s1, a_d1, row_ptr, srcs, b1, x2, n);

  gemm2_mfma<<<(n + 63) / 64, 256, 0, stream>>>(x2, w2t, as2, ad2, h2, a_s2, a_d2, n);
  gat_agg_l2<<<(n + 3) / 4, 256, 0, stream>>>(h2, a_s2, a_d2, row_ptr, srcs, b2, out, n);
}